// Round 15
// baseline (2423.570 us; speedup 1.0000x reference)
//
#include <hip/hip_runtime.h>
#include <hip/hip_fp16.h>

#define H     2048
#define LSEQ  512
#define NWG   256
#define TPB   512
#define UPW   8     // hidden units per WG
#define RPW   32    // gate rows per WG
#define KG    16    // k-groups per row

// ws float-index layout
#define WS_UA    0        // 512 floats
#define WS_GEN   512      // 1 int (prologue barrier)
#define WS_FLAGS 576      // 256*32 ints (prologue barrier flags)
#define WS_HPUB  10240    // 2 slots x 1024 u64 (tag32 | half2) = 4096 floats
#define WS_P     16384    // fp32 P: 8192*512 floats = 16 MB

typedef unsigned long long u64;
typedef unsigned int u32;

#define AT_LD(p)     __hip_atomic_load((p),  __ATOMIC_RELAXED, __HIP_MEMORY_SCOPE_SYSTEM)
#define AT_ST(p, v)  __hip_atomic_store((p), (v), __ATOMIC_RELAXED, __HIP_MEMORY_SCOPE_SYSTEM)

__device__ __forceinline__ float sigmoidf_(float v) { return 1.f / (1.f + __expf(-v)); }
__device__ __forceinline__ float tanhf_(float x) {
  float ax = fabsf(x);
  float e = __expf(-2.f * ax);
  float r = (1.f - e) / (1.f + e);
  return copysignf(r, x);
}

#if defined(__has_builtin)
#if __has_builtin(__builtin_amdgcn_fdot2)
#define HAVE_FDOT2 1
#endif
#endif
typedef _Float16 hh2 __attribute__((ext_vector_type(2)));

__device__ __forceinline__ float dot2acc(u32 a, u32 b, float c) {
#ifdef HAVE_FDOT2
  return __builtin_amdgcn_fdot2(__builtin_bit_cast(hh2, a), __builtin_bit_cast(hh2, b), c, false);
#else
  float2 af = __half22float2(*(__half2*)&a);
  float2 bf = __half22float2(*(__half2*)&b);
  return c + af.x * bf.x + af.y * bf.y;
#endif
}

__global__ void init_ws(float* ws) {
  int tid = threadIdx.x;
  u64* hPub = (u64*)(ws + WS_HPUB);
  for (int i = tid; i < 2048; i += 1024) hPub[i] = 0ull;   // tag=0, h=0 (both slots)
  int* gen = (int*)(ws + WS_GEN);
  int* flags = (int*)(ws + WS_FLAGS);
  if (tid == 0) *gen = 0;
  for (int i = tid; i < NWG * 32; i += 1024) flags[i] = 0;
}

// ---- one-time P = W_ih @ input^T (fp32)  ([8192,2048]x[512,2048]^T -> [8192,512]) ----
#define GP_BM 128
#define GP_BN 128
#define GP_BK 32
#define GP_PAD 5
__global__ __launch_bounds__(256) void gemm_P(const float* __restrict__ A,
                                              const float* __restrict__ B,
                                              float* __restrict__ P) {
  __shared__ float As[GP_BM][GP_BK + GP_PAD];
  __shared__ float Bs[GP_BN][GP_BK + GP_PAD];
  const int tid = threadIdx.x;
  const int bm = blockIdx.x, bn = blockIdx.y;
  const int tr = tid >> 4, tc = tid & 15;
  float acc[8][8] = {};
  for (int k0 = 0; k0 < H; k0 += GP_BK) {
    #pragma unroll
    for (int i = 0; i < 4; ++i) {
      int lin = tid + 256 * i;
      int r = lin >> 3, c4 = lin & 7;
      float4 va = *(const float4*)(A + (size_t)(bm * GP_BM + r) * H + k0 + c4 * 4);
      float4 vb = *(const float4*)(B + (size_t)(bn * GP_BN + r) * H + k0 + c4 * 4);
      As[r][c4 * 4 + 0] = va.x; As[r][c4 * 4 + 1] = va.y;
      As[r][c4 * 4 + 2] = va.z; As[r][c4 * 4 + 3] = va.w;
      Bs[r][c4 * 4 + 0] = vb.x; Bs[r][c4 * 4 + 1] = vb.y;
      Bs[r][c4 * 4 + 2] = vb.z; Bs[r][c4 * 4 + 3] = vb.w;
    }
    __syncthreads();
    #pragma unroll 8
    for (int k = 0; k < GP_BK; ++k) {
      float a[8], b[8];
      #pragma unroll
      for (int i = 0; i < 8; ++i) a[i] = As[tr * 8 + i][k];
      #pragma unroll
      for (int j = 0; j < 8; ++j) b[j] = Bs[tc * 8 + j][k];
      #pragma unroll
      for (int i = 0; i < 8; ++i)
        #pragma unroll
        for (int j = 0; j < 8; ++j) acc[i][j] += a[i] * b[j];
    }
    __syncthreads();
  }
  #pragma unroll
  for (int i = 0; i < 8; ++i)
    #pragma unroll
    for (int j4 = 0; j4 < 2; ++j4) {
      float4 v = make_float4(acc[i][j4 * 4], acc[i][j4 * 4 + 1],
                             acc[i][j4 * 4 + 2], acc[i][j4 * 4 + 3]);
      *(float4*)(P + (size_t)(bm * GP_BM + tr * 8 + i) * LSEQ + bn * GP_BN + tc * 8 + j4 * 4) = v;
    }
}

// ---------------- persistent main kernel (2 barriers/step, batched LDS reads) ----------------
__global__ __launch_bounds__(TPB, 1) void attn_rnn_main(
    const float* __restrict__ input, const float* __restrict__ bias_mat,
    const float* __restrict__ conv_w, const float* __restrict__ conv_b,
    const float* __restrict__ fc1_w, const float* __restrict__ fc1_b,
    const float* __restrict__ w_hh, const float* __restrict__ b_ih,
    const float* __restrict__ b_hh,
    const int* __restrict__ seq_len,
    float* __restrict__ out, float* __restrict__ ws)
{
  const int wg   = blockIdx.x;
  const int tid  = threadIdx.x;
  const int lane = tid & 63;
  const int wv   = tid >> 6;          // 0..7

  float* uaG   = ws + WS_UA;
  int*   genp  = (int*)(ws + WS_GEN);
  int*   flags = (int*)(ws + WS_FLAGS);
  u64*   hPub  = (u64*)(ws + WS_HPUB);   // [2][1024] (tag32 | half2)
  const float* Pf = ws + WS_P;

  __shared__ u32 h_u[1024];            // h as packed half2
  __shared__ float awave[8][LSEQ];     // per-wave attn e-values
  __shared__ float2 uab[LSEQ];         // (ua[l], bias[l])
  __shared__ float g_lds[RPW];
  __shared__ float fcp[8];             // per-wave fc1 partials
  __shared__ float red8p[8];           // prologue only
  __shared__ float c_state[UPW];
  __shared__ float h_tmp[UPW];

  const int r_local = tid >> 4;       // 0..31 (gate row within WG)
  const int kg      = tid & 15;       // 0..15 (k-group)
  const int gt      = r_local >> 3;   // gate type i,f,g,o
  const int u       = r_local & 7;    // unit within WG
  const int rg      = gt * H + wg * UPW + u;
  const float brow  = b_ih[rg] + b_hh[rg];

  // poll assignment: thread i watches WG (i>>1), word pair (i&1)*2
  const int pidx = (tid >> 1) * 4 + (tid & 1) * 2;

  // ---- ONE-TIME: weights -> registers (packed fp16), statically indexed ----
  u32 w_u[64];
  #pragma unroll
  for (int jj = 0; jj < 64; ++jj) {
    float2 wvv = *(const float2*)(w_hh + (size_t)rg * H + 2 * (jj * 16 + kg));
    __half2 p = __floats2half2_rn(wvv.x, wvv.y);
    w_u[jj] = *(u32*)&p;
  }
  u32 p_u[16];
  #pragma unroll
  for (int jj = 0; jj < 16; ++jj) {
    float2 pvv = *(const float2*)(Pf + (size_t)rg * LSEQ + 2 * (jj * 16 + kg));
    __half2 p = __floats2half2_rn(pvv.x, pvv.y);
    p_u[jj] = *(u32*)&p;
  }
  // fc1 weights matching this thread's POLLED h units (2*pidx .. 2*pidx+3)
  float2 f0 = *(const float2*)(fc1_w + 2 * pidx);
  float2 f1 = *(const float2*)(fc1_w + 2 * pidx + 2);
  #pragma unroll
  for (int jj = 0; jj < 64; ++jj) asm volatile("" : "+v"(w_u[jj]));
  #pragma unroll
  for (int jj = 0; jj < 16; ++jj) asm volatile("" : "+v"(p_u[jj]));
  asm volatile("" : "+v"(f0.x), "+v"(f0.y), "+v"(f1.x), "+v"(f1.y));

  if (tid < UPW) c_state[tid] = 0.f;

  // ---- ua[l] = input[l,:]·conv_w + conv_b  (WG owns l = 2wg, 2wg+1) ----
  const float cb = conv_b[0];
  #pragma unroll
  for (int li = 0; li < 2; ++li) {
    int l = wg * 2 + li;
    float4 rv = ((const float4*)(input + (size_t)l * H))[tid];
    float4 cv = ((const float4*)conv_w)[tid];
    float s = rv.x * cv.x + rv.y * cv.y + rv.z * cv.z + rv.w * cv.w;
    #pragma unroll
    for (int m = 32; m; m >>= 1) s += __shfl_xor(s, m);
    if (lane == 0) red8p[wv] = s;
    __syncthreads();
    if (tid == 0) {
      float v = cb;
      #pragma unroll
      for (int q = 0; q < 8; ++q) v += red8p[q];
      AT_ST(&uaG[l], v);
    }
    __syncthreads();
  }

  // prologue grid barrier (one-time, flag/gen)
  {
    const int ep = 1;
    if (wg == 0) {
      if (tid > 0 && tid < NWG) {
        while (AT_LD(&flags[tid * 32]) < ep) __builtin_amdgcn_s_sleep(2);
      }
      __syncthreads();
      if (tid == 0) __hip_atomic_store(genp, ep, __ATOMIC_RELEASE, __HIP_MEMORY_SCOPE_SYSTEM);
    } else {
      if (tid == 0) {
        __hip_atomic_store(&flags[wg * 32], ep, __ATOMIC_RELEASE, __HIP_MEMORY_SCOPE_SYSTEM);
        while (AT_LD(genp) < ep) __builtin_amdgcn_s_sleep(2);
      }
      __syncthreads();
    }
  }

  // step-invariant (ua, bias) pairs into LDS
  uab[tid & (LSEQ - 1)] = make_float2(AT_LD(&uaG[tid & (LSEQ - 1)]), bias_mat[tid & (LSEQ - 1)]);

  const int S = seq_len[0];
  const float fb = fc1_b[0];
  float* aw = awave[wv];

  __syncthreads();   // uab ready

  for (int t = 0; t < S; ++t) {
    // ---- rendezvous: tagged words + fc1 partial computed AT POLL TIME ----
    {
      const u64* slot = hPub + (size_t)(t & 1) * 1024;
      const u32 tt = (u32)t;
      u64 a = AT_LD(slot + pidx);
      u64 b = AT_LD(slot + pidx + 1);
      while (((u32)(a >> 32) < tt) || ((u32)(b >> 32) < tt)) {
        __builtin_amdgcn_s_sleep(1);
        if ((u32)(a >> 32) < tt) a = AT_LD(slot + pidx);
        if ((u32)(b >> 32) < tt) b = AT_LD(slot + pidx + 1);
      }
      u32 wa_ = (u32)a, wb_ = (u32)b;
      h_u[pidx]     = wa_;
      h_u[pidx + 1] = wb_;
      float2 h01 = __half22float2(*(__half2*)&wa_);
      float2 h23 = __half22float2(*(__half2*)&wb_);
      float fp = h01.x * f0.x + h01.y * f0.y + h23.x * f1.x + h23.y * f1.y;
      #pragma unroll
      for (int m = 32; m; m >>= 1) fp += __shfl_xor(fp, m);
      if (lane == 0) fcp[wv] = fp;
    }
    __syncthreads();                                  // S1: h + fcp ready

    // ---- w_a (batched reads, fixed combine order) ----
    float fv[8];
    #pragma unroll
    for (int q = 0; q < 8; ++q) fv[q] = fcp[q];
    float w_a = fb;
    #pragma unroll
    for (int q = 0; q < 8; ++q) w_a += fv[q];

    // ---- per-wave softmax, batched uab loads (MLP), no max subtraction ----
    float2 ub8[8];
    #pragma unroll
    for (int q = 0; q < 8; ++q) ub8[q] = uab[lane + 64 * q];
    float ev[8];
    #pragma unroll
    for (int q = 0; q < 8; ++q) {
      float v0 = ub8[q].x + w_a;
      float v = (v0 > 0.f ? v0 : 0.01f * v0) + ub8[q].y;  // leaky_relu then +bias
      ev[q] = __expf(v);
    }
    float sw = 0.f;
    #pragma unroll
    for (int q = 0; q < 8; ++q) {
      aw[lane + 64 * q] = ev[q];
      sw += ev[q];
    }
    #pragma unroll
    for (int m = 32; m; m >>= 1) sw += __shfl_xor(sw, m);
    const float inv = 1.f / sw;

    // ---- whh·h: batched h_u preloads (16-deep MLP) + 4 accumulators ----
    float a0h = 0.f, a1h = 0.f, a2h = 0.f, a3h = 0.f;
    #pragma unroll
    for (int blk = 0; blk < 4; ++blk) {
      u32 hb[16];
      #pragma unroll
      for (int m = 0; m < 16; ++m) hb[m] = h_u[(16 * blk + m) * 16 + kg];
      #pragma unroll
      for (int m = 0; m < 4; ++m) {
        a0h = dot2acc(w_u[16 * blk + 4 * m + 0], hb[4 * m + 0], a0h);
        a1h = dot2acc(w_u[16 * blk + 4 * m + 1], hb[4 * m + 1], a1h);
        a2h = dot2acc(w_u[16 * blk + 4 * m + 2], hb[4 * m + 2], a2h);
        a3h = dot2acc(w_u[16 * blk + 4 * m + 3], hb[4 * m + 3], a3h);
      }
    }
    float acc = (a0h + a1h) + (a2h + a3h);

    // ---- P·attn: batched aw preloads (8-deep MLP) ----
    float accp = 0.f;
    #pragma unroll
    for (int blk = 0; blk < 2; ++blk) {
      float2 e2b[8];
      #pragma unroll
      for (int m = 0; m < 8; ++m)
        e2b[m] = *(const float2*)(aw + 2 * ((8 * blk + m) * 16 + kg));
      #pragma unroll
      for (int m = 0; m < 8; ++m) {
        float2 pf = __half22float2(*(__half2*)&p_u[8 * blk + m]);
        accp += pf.x * e2b[m].x + pf.y * e2b[m].y;
      }
    }
    acc += accp * inv;
    acc += __shfl_xor(acc, 1);
    acc += __shfl_xor(acc, 2);
    acc += __shfl_xor(acc, 4);
    acc += __shfl_xor(acc, 8);
    if (kg == 0) g_lds[r_local] = acc + brow;
    __syncthreads();                                  // S2: gates ready

    // ---- LSTM (wave 0), publish FIRST, then out store ----
    float h_new;
    if (tid < UPW) {
      float iv = g_lds[tid], fv2 = g_lds[8 + tid], gv = g_lds[16 + tid], ov = g_lds[24 + tid];
      float c_new = sigmoidf_(fv2) * c_state[tid] + sigmoidf_(iv) * tanhf_(gv);
      h_new = sigmoidf_(ov) * tanhf_(c_new);
      c_state[tid] = c_new;
      h_tmp[tid] = h_new;
    }
    if (tid < 4) {   // same wave as h_tmp writers -> lgkmcnt ordering suffices
      __half2 hp = __floats2half2_rn(h_tmp[2 * tid], h_tmp[2 * tid + 1]);
      u64 word = ((u64)(u32)(t + 1) << 32) | (u64)(*(u32*)&hp);
      AT_ST(hPub + (size_t)((t + 1) & 1) * 1024 + wg * 4 + tid, word);
    }
    if (tid < UPW) {
      out[(size_t)t * H + wg * UPW + tid] = h_new;
    }
    // no trailing sync: next poll + S1 is the step boundary (self-inclusion safe)
  }
}

extern "C" void kernel_launch(void* const* d_in, const int* in_sizes, int n_in,
                              void* d_out, int out_size, void* d_ws, size_t ws_size,
                              hipStream_t stream) {
  const float* input    = (const float*)d_in[0];
  const float* bias_mat = (const float*)d_in[1];
  const float* conv_w   = (const float*)d_in[2];
  const float* conv_b   = (const float*)d_in[3];
  const float* fc1_w    = (const float*)d_in[4];
  const float* fc1_b    = (const float*)d_in[5];
  const float* w_ih     = (const float*)d_in[6];
  const float* b_ih     = (const float*)d_in[7];
  const float* w_hh     = (const float*)d_in[8];
  const float* b_hh     = (const float*)d_in[9];
  const int*   seqp     = (const int*)d_in[10];
  float* out = (float*)d_out;
  float* ws  = (float*)d_ws;

  hipLaunchKernelGGL(init_ws, dim3(1), dim3(1024), 0, stream, ws);
  hipLaunchKernelGGL(gemm_P, dim3(64, 4), dim3(256), 0, stream, w_ih, input, ws + WS_P);
  hipLaunchKernelGGL(attn_rnn_main, dim3(NWG), dim3(TPB), 0, stream,
                     input, bias_mat, conv_w, conv_b, fc1_w, fc1_b,
                     w_hh, b_ih, b_hh, seqp, out, ws);
}

// Round 18
// 2420.116 us; speedup vs baseline: 1.0014x; 1.0014x over previous
//
#include <hip/hip_runtime.h>
#include <hip/hip_fp16.h>

#define H     2048
#define LSEQ  512
#define NWG   256
#define TPB   512
#define UPW   8     // hidden units per WG
#define RPW   32    // gate rows per WG
#define KG    16    // k-groups per row

// ws float-index layout
#define WS_UA    0        // 512 floats
#define WS_GEN   512      // 1 int (prologue barrier)
#define WS_FLAGS 576      // 256*32 ints (prologue barrier flags)
#define WS_HPUB  10240    // 2 slots x 1024 u64 (tag32 | half2) = 4096 floats
#define WS_P     16384    // fp32 P: 8192*512 floats = 16 MB

typedef unsigned long long u64;
typedef unsigned int u32;

// SYSTEM scope (proven R9-R15): relaxed system atomics are served at the MALL
// coherence point (sc0 sc1 -> bypass the non-coherent per-XCD L2) with no
// per-iteration cache invalidation. AGENT scope reverted (R16 suspect).
#define AT_LD(p)     __hip_atomic_load((p),  __ATOMIC_RELAXED, __HIP_MEMORY_SCOPE_SYSTEM)
#define AT_ST(p, v)  __hip_atomic_store((p), (v), __ATOMIC_RELAXED, __HIP_MEMORY_SCOPE_SYSTEM)

__device__ __forceinline__ float sigmoidf_(float v) { return 1.f / (1.f + __expf(-v)); }
__device__ __forceinline__ float tanhf_(float x) {
  float ax = fabsf(x);
  float e = __expf(-2.f * ax);
  float r = (1.f - e) / (1.f + e);
  return copysignf(r, x);
}

#if defined(__has_builtin)
#if __has_builtin(__builtin_amdgcn_fdot2)
#define HAVE_FDOT2 1
#endif
#endif
typedef _Float16 hh2 __attribute__((ext_vector_type(2)));

__device__ __forceinline__ float dot2acc(u32 a, u32 b, float c) {
#ifdef HAVE_FDOT2
  return __builtin_amdgcn_fdot2(__builtin_bit_cast(hh2, a), __builtin_bit_cast(hh2, b), c, false);
#else
  float2 af = __half22float2(*(__half2*)&a);
  float2 bf = __half22float2(*(__half2*)&b);
  return c + af.x * bf.x + af.y * bf.y;
#endif
}

__global__ void init_ws(float* ws) {
  int tid = threadIdx.x;
  u64* hPub = (u64*)(ws + WS_HPUB);
  for (int i = tid; i < 2048; i += 1024) hPub[i] = 0ull;   // tag=0, h=0 (both slots)
  int* gen = (int*)(ws + WS_GEN);
  int* flags = (int*)(ws + WS_FLAGS);
  if (tid == 0) *gen = 0;
  for (int i = tid; i < NWG * 32; i += 1024) flags[i] = 0;
}

// ---- one-time P = W_ih @ input^T (fp32)  ([8192,2048]x[512,2048]^T -> [8192,512]) ----
#define GP_BM 128
#define GP_BN 128
#define GP_BK 32
#define GP_PAD 5
__global__ __launch_bounds__(256) void gemm_P(const float* __restrict__ A,
                                              const float* __restrict__ B,
                                              float* __restrict__ P) {
  __shared__ float As[GP_BM][GP_BK + GP_PAD];
  __shared__ float Bs[GP_BN][GP_BK + GP_PAD];
  const int tid = threadIdx.x;
  const int bm = blockIdx.x, bn = blockIdx.y;
  const int tr = tid >> 4, tc = tid & 15;
  float acc[8][8] = {};
  for (int k0 = 0; k0 < H; k0 += GP_BK) {
    #pragma unroll
    for (int i = 0; i < 4; ++i) {
      int lin = tid + 256 * i;
      int r = lin >> 3, c4 = lin & 7;
      float4 va = *(const float4*)(A + (size_t)(bm * GP_BM + r) * H + k0 + c4 * 4);
      float4 vb = *(const float4*)(B + (size_t)(bn * GP_BN + r) * H + k0 + c4 * 4);
      As[r][c4 * 4 + 0] = va.x; As[r][c4 * 4 + 1] = va.y;
      As[r][c4 * 4 + 2] = va.z; As[r][c4 * 4 + 3] = va.w;
      Bs[r][c4 * 4 + 0] = vb.x; Bs[r][c4 * 4 + 1] = vb.y;
      Bs[r][c4 * 4 + 2] = vb.z; Bs[r][c4 * 4 + 3] = vb.w;
    }
    __syncthreads();
    #pragma unroll 8
    for (int k = 0; k < GP_BK; ++k) {
      float a[8], b[8];
      #pragma unroll
      for (int i = 0; i < 8; ++i) a[i] = As[tr * 8 + i][k];
      #pragma unroll
      for (int j = 0; j < 8; ++j) b[j] = Bs[tc * 8 + j][k];
      #pragma unroll
      for (int i = 0; i < 8; ++i)
        #pragma unroll
        for (int j = 0; j < 8; ++j) acc[i][j] += a[i] * b[j];
    }
    __syncthreads();
  }
  #pragma unroll
  for (int i = 0; i < 8; ++i)
    #pragma unroll
    for (int j4 = 0; j4 < 2; ++j4) {
      float4 v = make_float4(acc[i][j4 * 4], acc[i][j4 * 4 + 1],
                             acc[i][j4 * 4 + 2], acc[i][j4 * 4 + 3]);
      *(float4*)(P + (size_t)(bm * GP_BM + tr * 8 + i) * LSEQ + bn * GP_BN + tc * 8 + j4 * 4) = v;
    }
}

// ---------------- persistent main kernel (2 barriers/step, shfl publish pack) ----------------
__global__ __launch_bounds__(TPB, 1) void attn_rnn_main(
    const float* __restrict__ input, const float* __restrict__ bias_mat,
    const float* __restrict__ conv_w, const float* __restrict__ conv_b,
    const float* __restrict__ fc1_w, const float* __restrict__ fc1_b,
    const float* __restrict__ w_hh, const float* __restrict__ b_ih,
    const float* __restrict__ b_hh,
    const int* __restrict__ seq_len,
    float* __restrict__ out, float* __restrict__ ws)
{
  const int wg   = blockIdx.x;
  const int tid  = threadIdx.x;
  const int lane = tid & 63;
  const int wv   = tid >> 6;          // 0..7

  float* uaG   = ws + WS_UA;
  int*   genp  = (int*)(ws + WS_GEN);
  int*   flags = (int*)(ws + WS_FLAGS);
  u64*   hPub  = (u64*)(ws + WS_HPUB);   // [2][1024] (tag32 | half2)
  const float* Pf = ws + WS_P;

  __shared__ u32 h_u[1024];            // h as packed half2
  __shared__ float awave[8][LSEQ];     // per-wave attn e-values
  __shared__ float2 uab[LSEQ];         // (ua[l], bias[l])
  __shared__ float g_lds[RPW];
  __shared__ float fcp[8];             // per-wave fc1 partials
  __shared__ float red8p[8];           // prologue only

  const int r_local = tid >> 4;       // 0..31 (gate row within WG)
  const int kg      = tid & 15;       // 0..15 (k-group)
  const int gt      = r_local >> 3;   // gate type i,f,g,o
  const int u       = r_local & 7;    // unit within WG
  const int rg      = gt * H + wg * UPW + u;
  const float brow  = b_ih[rg] + b_hh[rg];

  // poll assignment: thread i watches WG (i>>1), word pair (i&1)*2
  const int pidx = (tid >> 1) * 4 + (tid & 1) * 2;

  // ---- ONE-TIME: weights -> registers (packed fp16), statically indexed ----
  u32 w_u[64];
  #pragma unroll
  for (int jj = 0; jj < 64; ++jj) {
    float2 wvv = *(const float2*)(w_hh + (size_t)rg * H + 2 * (jj * 16 + kg));
    __half2 p = __floats2half2_rn(wvv.x, wvv.y);
    w_u[jj] = *(u32*)&p;
  }
  u32 p_u[16];
  #pragma unroll
  for (int jj = 0; jj < 16; ++jj) {
    float2 pvv = *(const float2*)(Pf + (size_t)rg * LSEQ + 2 * (jj * 16 + kg));
    __half2 p = __floats2half2_rn(pvv.x, pvv.y);
    p_u[jj] = *(u32*)&p;
  }
  // fc1 weights matching this thread's POLLED h units (2*pidx .. 2*pidx+3)
  float2 f0 = *(const float2*)(fc1_w + 2 * pidx);
  float2 f1 = *(const float2*)(fc1_w + 2 * pidx + 2);
  #pragma unroll
  for (int jj = 0; jj < 64; ++jj) asm volatile("" : "+v"(w_u[jj]));
  #pragma unroll
  for (int jj = 0; jj < 16; ++jj) asm volatile("" : "+v"(p_u[jj]));
  asm volatile("" : "+v"(f0.x), "+v"(f0.y), "+v"(f1.x), "+v"(f1.y));

  float c_st = 0.f;   // cell state of unit `lane` (valid in wave-0 lanes 0..7)

  // ---- ua[l] = input[l,:]·conv_w + conv_b  (WG owns l = 2wg, 2wg+1) ----
  const float cb = conv_b[0];
  #pragma unroll
  for (int li = 0; li < 2; ++li) {
    int l = wg * 2 + li;
    float4 rv = ((const float4*)(input + (size_t)l * H))[tid];
    float4 cv = ((const float4*)conv_w)[tid];
    float s = rv.x * cv.x + rv.y * cv.y + rv.z * cv.z + rv.w * cv.w;
    #pragma unroll
    for (int m = 32; m; m >>= 1) s += __shfl_xor(s, m);
    if (lane == 0) red8p[wv] = s;
    __syncthreads();
    if (tid == 0) {
      float v = cb;
      #pragma unroll
      for (int q = 0; q < 8; ++q) v += red8p[q];
      AT_ST(&uaG[l], v);
    }
    __syncthreads();
  }

  // prologue grid barrier (one-time, flag/gen)
  {
    const int ep = 1;
    if (wg == 0) {
      if (tid > 0 && tid < NWG) {
        while (AT_LD(&flags[tid * 32]) < ep) __builtin_amdgcn_s_sleep(2);
      }
      __syncthreads();
      if (tid == 0) __hip_atomic_store(genp, ep, __ATOMIC_RELEASE, __HIP_MEMORY_SCOPE_SYSTEM);
    } else {
      if (tid == 0) {
        __hip_atomic_store(&flags[wg * 32], ep, __ATOMIC_RELEASE, __HIP_MEMORY_SCOPE_SYSTEM);
        while (AT_LD(genp) < ep) __builtin_amdgcn_s_sleep(2);
      }
      __syncthreads();
    }
  }

  // step-invariant (ua, bias) pairs into LDS
  uab[tid & (LSEQ - 1)] = make_float2(AT_LD(&uaG[tid & (LSEQ - 1)]), bias_mat[tid & (LSEQ - 1)]);

  const int S = seq_len[0];
  const float fb = fc1_b[0];
  float* aw = awave[wv];

  __syncthreads();   // uab ready

  for (int t = 0; t < S; ++t) {
    // ---- rendezvous: tagged words + fc1 partial computed AT POLL TIME ----
    {
      const u64* slot = hPub + (size_t)(t & 1) * 1024;
      const u32 tt = (u32)t;
      u64 a = AT_LD(slot + pidx);
      u64 b = AT_LD(slot + pidx + 1);
      while (((u32)(a >> 32) < tt) || ((u32)(b >> 32) < tt)) {
        __builtin_amdgcn_s_sleep(1);
        if ((u32)(a >> 32) < tt) a = AT_LD(slot + pidx);
        if ((u32)(b >> 32) < tt) b = AT_LD(slot + pidx + 1);
      }
      u32 wa_ = (u32)a, wb_ = (u32)b;
      h_u[pidx]     = wa_;
      h_u[pidx + 1] = wb_;
      float2 h01 = __half22float2(*(__half2*)&wa_);
      float2 h23 = __half22float2(*(__half2*)&wb_);
      float fp = h01.x * f0.x + h01.y * f0.y + h23.x * f1.x + h23.y * f1.y;
      #pragma unroll
      for (int m = 32; m; m >>= 1) fp += __shfl_xor(fp, m);
      if (lane == 0) fcp[wv] = fp;
    }
    __syncthreads();                                  // S1: h + fcp ready

    // ---- w_a (fixed combine order) ----
    float w_a = fb;
    #pragma unroll
    for (int q = 0; q < 8; ++q) w_a += fcp[q];

    // ---- per-wave softmax, no max subtraction (shift-invariant; logits bounded) ----
    float sw = 0.f;
    #pragma unroll
    for (int q = 0; q < 8; ++q) {
      float2 ub = uab[lane + 64 * q];
      float v0 = ub.x + w_a;
      float v = (v0 > 0.f ? v0 : 0.01f * v0) + ub.y;  // leaky_relu then +bias
      float e = __expf(v);
      aw[lane + 64 * q] = e;
      sw += e;
    }
    #pragma unroll
    for (int m = 32; m; m >>= 1) sw += __shfl_xor(sw, m);
    const float inv = 1.f / sw;

    // ---- whh·h (regs x LDS) + P·attn (regs x same-wave LDS e-values) ----
    float a0h = 0.f, a1h = 0.f, a2h = 0.f, a3h = 0.f;
    #pragma unroll
    for (int jj = 0; jj < 16; ++jj) {
      a0h = dot2acc(w_u[4 * jj + 0], h_u[(4 * jj + 0) * 16 + kg], a0h);
      a1h = dot2acc(w_u[4 * jj + 1], h_u[(4 * jj + 1) * 16 + kg], a1h);
      a2h = dot2acc(w_u[4 * jj + 2], h_u[(4 * jj + 2) * 16 + kg], a2h);
      a3h = dot2acc(w_u[4 * jj + 3], h_u[(4 * jj + 3) * 16 + kg], a3h);
    }
    float acc = (a0h + a1h) + (a2h + a3h);
    float accp = 0.f;
    #pragma unroll
    for (int jj = 0; jj < 16; ++jj) {
      float2 e2 = *(const float2*)(aw + 2 * (jj * 16 + kg));
      float2 pf = __half22float2(*(__half2*)&p_u[jj]);
      accp += pf.x * e2.x + pf.y * e2.y;
    }
    acc += accp * inv;
    acc += __shfl_xor(acc, 1);
    acc += __shfl_xor(acc, 2);
    acc += __shfl_xor(acc, 4);
    acc += __shfl_xor(acc, 8);
    if (kg == 0) g_lds[r_local] = acc + brow;
    __syncthreads();                                  // S2: gates ready

    // ---- LSTM (wave 0, c in regs) + shfl pack + publish, then out store ----
    if (wv == 0) {
      float h_new = 0.f;
      if (lane < UPW) {
        float iv = g_lds[lane], fv2 = g_lds[8 + lane],
              gv = g_lds[16 + lane], ov = g_lds[24 + lane];
        float c_new = sigmoidf_(fv2) * c_st + sigmoidf_(iv) * tanhf_(gv);
        h_new = sigmoidf_(ov) * tanhf_(c_new);
        c_st = c_new;
      }
      // lanes 0..3 gather pairs via shfl (sources 0..7 hold valid h_new)
      float hlo = __shfl(h_new, 2 * lane);
      float hhi = __shfl(h_new, 2 * lane + 1);
      if (lane < 4) {
        __half2 hp = __floats2half2_rn(hlo, hhi);
        u64 word = ((u64)(u32)(t + 1) << 32) | (u64)(*(u32*)&hp);
        AT_ST(hPub + (size_t)((t + 1) & 1) * 1024 + wg * 4 + lane, word);
      }
      if (lane < UPW) {
        out[(size_t)t * H + wg * UPW + lane] = h_new;
      }
    }
    // no trailing sync: next poll + S1 is the step boundary (self-inclusion safe)
  }
}

extern "C" void kernel_launch(void* const* d_in, const int* in_sizes, int n_in,
                              void* d_out, int out_size, void* d_ws, size_t ws_size,
                              hipStream_t stream) {
  const float* input    = (const float*)d_in[0];
  const float* bias_mat = (const float*)d_in[1];
  const float* conv_w   = (const float*)d_in[2];
  const float* conv_b   = (const float*)d_in[3];
  const float* fc1_w    = (const float*)d_in[4];
  const float* fc1_b    = (const float*)d_in[5];
  const float* w_ih     = (const float*)d_in[6];
  const float* b_ih     = (const float*)d_in[7];
  const float* w_hh     = (const float*)d_in[8];
  const float* b_hh     = (const float*)d_in[9];
  const int*   seqp     = (const int*)d_in[10];
  float* out = (float*)d_out;
  float* ws  = (float*)d_ws;

  hipLaunchKernelGGL(init_ws, dim3(1), dim3(1024), 0, stream, ws);
  hipLaunchKernelGGL(gemm_P, dim3(64, 4), dim3(256), 0, stream, w_ih, input, ws + WS_P);
  hipLaunchKernelGGL(attn_rnn_main, dim3(NWG), dim3(TPB), 0, stream,
                     input, bias_mat, conv_w, conv_b, fc1_w, fc1_b,
                     w_hh, b_ih, b_hh, seqp, out, ws);
}